// Round 8
// baseline (2717.555 us; speedup 1.0000x reference)
//
#include <hip/hip_runtime.h>
#include <cstddef>

#define B_  64
#define T_  256
#define I_  256
#define H_  1024
#define C_  1000
#define BH_ (B_ * H_)
#define SLOTS_B_ 24        // ring length for the mid-size workspace tier

typedef _Float16 f16;
typedef __attribute__((ext_vector_type(8))) _Float16 f16x8;
typedef __attribute__((ext_vector_type(4))) float f32x4;

__device__ __forceinline__ float sigmoid_(float v) { return 1.0f / (1.0f + __expf(-v)); }
__device__ __forceinline__ float tanh_(float v) {
  float e = __expf(-2.0f * fabsf(v));
  float t = (1.0f - e) / (1.0f + e);
  return copysignf(t, v);
}

// h store: agent-scope relaxed atomic store -> write-through dword.
// R7 lesson #2: the fancy 16B asm-store + shuffle-pack variant REGRESSED
// (serialized epilogue scheduling); per-thread 4B pair stores issue early
// and drain under other waves' epilogue work. Keep R4's form.
__device__ __forceinline__ void storeH2(f16* p, float a, float b) {
  union { f16 h[2]; unsigned u; } pk;
  pk.h[0] = (f16)a; pk.h[1] = (f16)b;
  __hip_atomic_store((unsigned*)p, pk.u, __ATOMIC_RELAXED, __HIP_MEMORY_SCOPE_AGENT);
}

// ---------------- sync protocol (R2 leaderless min-gate) ----------------
// 4 closures of 64 blocks: C(layer,mgroup); 8 arrival counters each (128B
// lines), 8 adder-blocks per counter. Gate = min over own closure's 8
// counters >= 8p (induction: first block seeing min>=8p forces all counts=p;
// holds regardless of WHERE in the phase the gate sits, since the (p+1)th
// add always happens after passing the phase-p gate).
// Adds AFTER the barrier's vmcnt(0) drain => observed arrival implies that
// block's h stores are visible at MALL.
// R8: L1's two gates merge into ONE 16-line poll at phase top -- one load
// burst = 1 fabric RT instead of 2 serial RTs (R6 instrumentation: waits are
// ~0-7%, so the satisfied-poll ROUND TRIP is the cost, not the wait).

__device__ __forceinline__ unsigned ldS(unsigned* p) {
  return __hip_atomic_load(p, __ATOMIC_RELAXED, __HIP_MEMORY_SCOPE_AGENT);
}

__device__ __forceinline__ void sleepN(int lvl) {
  switch (lvl) {
    case 0: __builtin_amdgcn_s_sleep(1); break;
    case 1: __builtin_amdgcn_s_sleep(2); break;
    case 2: __builtin_amdgcn_s_sleep(4); break;
    default: __builtin_amdgcn_s_sleep(8); break;
  }
}

__device__ __forceinline__ void waitCtr8(unsigned* base, unsigned tgt) {
  unsigned mn = 0xffffffffu;
#pragma unroll
  for (int j = 0; j < 8; ++j) {
    unsigned v = ldS(base + j * 32);
    mn = (v < mn) ? v : mn;
  }
  if (mn >= tgt) return;                         // fast path: 1 RT
  int lvl = 0, g = 0;
  for (;;) {
    mn = 0xffffffffu;
#pragma unroll
    for (int j = 0; j < 8; ++j) {
      unsigned v = ldS(base + j * 32);
      mn = (v < mn) ? v : mn;
    }
    if (mn >= tgt) break;
    sleepN(lvl);
    if (lvl < 3) ++lvl;
    if (++g > (1 << 17)) break;
  }
}

// both closures' 8 lines in one 16-load burst (1 RT when satisfied)
__device__ __forceinline__ void waitCtr16(unsigned* b0, unsigned t0,
                                          unsigned* b1, unsigned t1) {
  int lvl = 0, g = 0;
  for (;;) {
    unsigned m0 = 0xffffffffu, m1 = 0xffffffffu;
#pragma unroll
    for (int j = 0; j < 8; ++j) {
      unsigned v0 = ldS(b0 + j * 32);
      unsigned v1 = ldS(b1 + j * 32);
      m0 = (v0 < m0) ? v0 : m0;
      m1 = (v1 < m1) ? v1 : m1;
    }
    if (m0 >= t0 && m1 >= t1) return;
    sleepN(lvl);
    if (lvl < 3) ++lvl;
    if (++g > (1 << 17)) return;
  }
}

// One block = 512 threads = 8 waves = (K-split 4) x (N-split 2).
// Block tile: 32 batch rows x 64 gate-cols (4 gates x 16 units).
// k-tile map (per wave kq):
//   L0: ii<2 -> x-tile (immutable, computed PRE-gate); ii>=2 -> h0-tile.
//   L1: ii<8 -> h0-tile; ii>=8 -> h1-tile (both gated at phase top, R8).
// CRITICAL: prologue loop must stay FULLY unrolled so Wreg indexing is static.
template<bool IS_L1>
__device__ __forceinline__ void role_main(
    const f16* __restrict__ x16,
    const float* __restrict__ Wx, const float* __restrict__ Wh,
    const float* __restrict__ bias,
    f16* __restrict__ h0hist, f16* __restrict__ h1hist,
    unsigned* sync, int bid, int nslots, int fmask, int lagD,
    float* zbAll, float* cLDS, float* biasLDS)
{
  constexpr int NKT   = IS_L1 ? 16 : 10;   // k-tiles of 32 per wave
  constexpr int KX    = IS_L1 ? 1024 : 256;
  constexpr int NSLOT = IS_L1 ? 10 : 8;    // A-frag ring (+2 for L1 batch fuse)

  const int tid  = threadIdx.x;
  const int wv   = tid >> 6;          // 0..7
  const int nh   = wv >> 2;           // col-half (32 cols each)
  const int kq   = wv & 3;            // K quarter
  const int lane = tid & 63;
  const int c16  = lane & 15;
  const int quad = lane >> 4;
  const int rr7  = bid & 127;
  const int mgroup  = rr7 & 1;
  const int ubase   = (rr7 >> 1) * 16;
  const int rowbase = mgroup * 32;

  const int sub = (rr7 >> 1) & 7;
  unsigned* ctrC0 = sync + ((0 * 2 + mgroup) * 8) * 32;
  unsigned* ctrC1 = sync + ((1 * 2 + mgroup) * 8) * 32;
  unsigned* arrLine = (IS_L1 ? ctrC1 : ctrC0) + sub * 32;

  auto kmap = [&](int ii) -> int {
    if (!IS_L1) return (ii < 2) ? (kq * 2 + ii) * 32 : 256 + (kq * 8 + (ii - 2)) * 32;
    else        return (ii < 8) ? (kq * 8 + ii) * 32 : 1024 + (kq * 8 + (ii - 8)) * 32;
  };

  if (tid < 64) biasLDS[tid] = bias[(size_t)(tid >> 4) * H_ + ubase + (tid & 15)];
  cLDS[tid] = 0.0f;

  // ---- weight prologue: global fp32 -> per-wave LDS panel -> f16 B-frags
  f16x8 Wreg[2][NKT];
  {
    f16* zpan = (f16*)zbAll + wv * 1024;
#pragma unroll
    for (int ii = 0; ii < NKT; ++ii) {
      const int kbase = kmap(ii);
#pragma unroll
      for (int rw = 0; rw < 16; ++rw) {
        const int krow  = rw * 2 + (lane >> 5);
        const int col32 = lane & 31;
        const int g = nh * 2 + (col32 >> 4);
        const int u = col32 & 15;
        const int k = kbase + krow;
        float wval = (k < KX) ? Wx[((size_t)g * KX + k) * H_ + ubase + u]
                              : Wh[((size_t)g * H_ + (k - KX)) * H_ + ubase + u];
        zpan[krow * 32 + col32] = (f16)wval;
      }
#pragma unroll
      for (int nt = 0; nt < 2; ++nt) {
        f16x8 f;
#pragma unroll
        for (int j = 0; j < 8; ++j)
          f[j] = zpan[(quad * 8 + j) * 32 + nt * 16 + c16];
        Wreg[nt][ii] = f;
      }
    }
  }
  __syncthreads();

  const int row0 = rowbase + c16;

  f32x4 acc[2][2];
  f16x8 Abuf[NSLOT][2];

  auto zeroAcc = [&]() {
#pragma unroll
    for (int mt2 = 0; mt2 < 2; ++mt2)
#pragma unroll
      for (int nt = 0; nt < 2; ++nt)
        acc[mt2][nt] = (f32x4)0.0f;
  };
  auto mfma4 = [&](int slot, int ii) {
    const f16x8 a0 = Abuf[slot][0];
    const f16x8 a1 = Abuf[slot][1];
    acc[0][0] = __builtin_amdgcn_mfma_f32_16x16x32_f16(a0, Wreg[0][ii], acc[0][0], 0, 0, 0);
    acc[0][1] = __builtin_amdgcn_mfma_f32_16x16x32_f16(a0, Wreg[1][ii], acc[0][1], 0, 0, 0);
    acc[1][0] = __builtin_amdgcn_mfma_f32_16x16x32_f16(a1, Wreg[0][ii], acc[1][0], 0, 0, 0);
    acc[1][1] = __builtin_amdgcn_mfma_f32_16x16x32_f16(a1, Wreg[1][ii], acc[1][1], 0, 0, 0);
  };
  auto loadH = [&](const f16* base, int ii, int slot) {
    const int kb = kmap(ii) + quad * 8;
    const int koff = (IS_L1 && ii >= 8) ? (kb - 1024) : (IS_L1 ? kb : (kb - 256));
#pragma unroll
    for (int mt2 = 0; mt2 < 2; ++mt2) {
      const int row = row0 + mt2 * 16;
      Abuf[slot][mt2] = *(const f16x8*)(base + (size_t)row * H_ + koff);
    }
  };
  auto loadX = [&](int pp, int ii, int slot) {
    const int kb = kmap(ii) + quad * 8;
#pragma unroll
    for (int mt2 = 0; mt2 < 2; ++mt2) {
      const int row = row0 + mt2 * 16;
      Abuf[slot][mt2] = *(const f16x8*)(x16 + ((size_t)row * T_ + pp) * I_ + kb);
    }
  };

  // epilogue: z partials -> LDS reduce -> gates -> h store (R4-exact)
  auto epilogue = [&](f16* hdst) {
    float* zw = zbAll + (nh * 4 + kq) * 1024;
#pragma unroll
    for (int mt2 = 0; mt2 < 2; ++mt2)
#pragma unroll
      for (int nt = 0; nt < 2; ++nt)
#pragma unroll
        for (int e = 0; e < 4; ++e)
          zw[(mt2 * 2 + nt) * 256 + (quad * 4 + e) * 16 + c16] = acc[mt2][nt][e];
    __syncthreads();
    {
      const int base = tid * 4;
      const int nh1  = base >> 10;
      const int off  = base & 1023;
      f32x4 s = (f32x4)0.0f;
#pragma unroll
      for (int q = 0; q < 4; ++q)
        s += *(const f32x4*)(zbAll + nh1 * 4096 + q * 1024 + off);
      const int nt1 = (off >> 8) & 1;
      const int c0  = off & 15;
      s += *(const f32x4*)(biasLDS + (nh1 * 2 + nt1) * 16 + c0);
      *(f32x4*)(zbAll + nh1 * 4096 + off) = s;
    }
    __syncthreads();
    {
      const int row = tid >> 4, u = tid & 15;
      const int mt2 = row >> 4, r16 = row & 15;
      const float z0 = zbAll[0 * 4096 + (mt2 * 2 + 0) * 256 + r16 * 16 + u];
      const float z1 = zbAll[0 * 4096 + (mt2 * 2 + 1) * 256 + r16 * 16 + u];
      const float z2 = zbAll[1 * 4096 + (mt2 * 2 + 0) * 256 + r16 * 16 + u];
      const float z3 = zbAll[1 * 4096 + (mt2 * 2 + 1) * 256 + r16 * 16 + u];
      const float cv = cLDS[tid];
      const float gt = tanh_(z0);
      const float iv = sigmoid_(z1);
      const float fv = sigmoid_(z2);
      const float ov = sigmoid_(z3);
      const float cn = gt * iv + cv * fv;
      cLDS[tid] = cn;
      const float hn = tanh_(cn) * ov;
      const float hn_hi = __shfl_down(hn, 1);
      if ((tid & 1) == 0)
        storeH2(hdst + (size_t)(rowbase + row) * H_ + ubase + u, hn, hn_hi);
    }
  };

#pragma unroll 1
  for (int p = 0; p <= T_; ++p) {
    const bool active = IS_L1 ? (p >= 1) : (p < T_);
    const int do_fence = (nslots == 2) ? 1
                        : ((fmask < 0) ? 0 : (((p & fmask) == fmask) ? 1 : 0));

    if (active) {
      const int sp  = p % nslots;
      const int spm = (p - 1 + nslots) % nslots;
      const int spp = (p + 1) % nslots;

      zeroAcc();
      if constexpr (!IS_L1) {
        // pre-gate x-part (immutable input, off the critical chain)
        loadX(p, 0, 0); loadX(p, 1, 1);
        mfma4(0, 0); mfma4(1, 1);
        if (tid == 0) {
          waitCtr8(ctrC0, 8u * (unsigned)p);
          if (lagD >= 0 && p > lagD) waitCtr8(ctrC1, 8u * (unsigned)(p - lagD));
          if (do_fence) __builtin_amdgcn_fence(__ATOMIC_ACQUIRE, "agent");
        }
        __syncthreads();
        const f16* hA = h0hist + (size_t)sp * BH_;
        f16* hdst = h0hist + (size_t)spp * BH_;
#pragma unroll
        for (int ii = 2; ii < 10; ++ii) loadH(hA, ii, ii - 2);
#pragma unroll
        for (int ii = 2; ii < 10; ++ii) mfma4(ii - 2, ii);
        epilogue(hdst);
      } else {
        // R8: ONE merged gate (16-line burst) covering h0[p-1] AND h1[p-2]
        if (tid == 0) {
          waitCtr16(ctrC0, 8u * (unsigned)p, ctrC1, 8u * (unsigned)p);
          if (do_fence) __builtin_amdgcn_fence(__ATOMIC_ACQUIRE, "agent");
        }
        __syncthreads();
        const f16* hA = h0hist + (size_t)sp * BH_;
        const f16* hB = h1hist + (size_t)spm * BH_;
        f16* hdst = h1hist + (size_t)sp * BH_;
        // fused load batch: 10 tiles up-front (one latency window), the
        // remaining 6 hB tiles trickle into freed slots under the hA MFMAs
#pragma unroll
        for (int ii = 0; ii < 8; ++ii) loadH(hA, ii, ii);
        loadH(hB, 8, 8); loadH(hB, 9, 9);
#pragma unroll
        for (int ii = 0; ii < 8; ++ii) mfma4(ii, ii);
        loadH(hB, 10, 0); loadH(hB, 11, 1); loadH(hB, 12, 2);
        loadH(hB, 13, 3); loadH(hB, 14, 4); loadH(hB, 15, 5);
        mfma4(8, 8); mfma4(9, 9);
        mfma4(0, 10); mfma4(1, 11); mfma4(2, 12);
        mfma4(3, 13); mfma4(4, 14); mfma4(5, 15);
        epilogue(hdst);
      }
    }

    __syncthreads();   // vmcnt(0) drain: all waves' h stores visible at MALL
    if (tid == 0)
      __hip_atomic_fetch_add(arrLine, 1u, __ATOMIC_RELAXED, __HIP_MEMORY_SCOPE_AGENT);
  }
}

__global__ __launch_bounds__(512, 2)
void lstm_persistent(const f16* __restrict__ x16,
                     const float* __restrict__ W0x, const float* __restrict__ W0h, const float* __restrict__ b0,
                     const float* __restrict__ W1x, const float* __restrict__ W1h, const float* __restrict__ b1,
                     f16* h0hist, f16* h1hist, unsigned* sync,
                     int nslots, int fmask, int lagD)
{
  __shared__ float zbAll[8192];    // 32KB: prologue panels / partial z / final z
  __shared__ float cLDS[512];
  __shared__ float biasLDS[64];
  const int bid = blockIdx.x;
  if (bid >= 128)
    role_main<true >(x16, W1x, W1h, b1, h0hist, h1hist, sync, bid, nslots, fmask, lagD, zbAll, cLDS, biasLDS);
  else
    role_main<false>(x16, W0x, W0h, b0, h0hist, h1hist, sync, bid, nslots, fmask, lagD, zbAll, cLDS, biasLDS);
}

// x fp32 -> f16, once
__global__ void cvt_x(const float* __restrict__ xin, f16* __restrict__ xo)
{
  const int i = (blockIdx.x * 256 + threadIdx.x) * 8;
  const float4 a = *(const float4*)(xin + i);
  const float4 b = *(const float4*)(xin + i + 4);
  f16x8 v;
  v[0] = (f16)a.x; v[1] = (f16)a.y; v[2] = (f16)a.z; v[3] = (f16)a.w;
  v[4] = (f16)b.x; v[5] = (f16)b.y; v[6] = (f16)b.z; v[7] = (f16)b.w;
  *(f16x8*)(xo + i) = v;
}

// out[b][c] = h1_final[b][:] . Wo[:][c] + bo[c]   (fp32 vector math)
__global__ void out_gemm(const f16* __restrict__ h1,
                         const float* __restrict__ Wo, const float* __restrict__ bo,
                         float* __restrict__ out)
{
  __shared__ float ht[1024][8];
  const int tid = threadIdx.x;    // 128 threads
  const int b0r = blockIdx.y * 4;
  for (int i = tid; i < 4096; i += 128) {
    const int rr = i >> 10, k = i & 1023;
    ht[k][rr] = (float)h1[(size_t)(b0r + rr) * H_ + k];
  }
  __syncthreads();
  const int c = blockIdx.x * 125 + tid;
  if (tid < 125) {
    float a0 = 0.f, a1 = 0.f, a2 = 0.f, a3 = 0.f;
#pragma unroll 4
    for (int k = 0; k < 1024; ++k) {
      const float w = Wo[(size_t)k * C_ + c];
      a0 += ht[k][0] * w;
      a1 += ht[k][1] * w;
      a2 += ht[k][2] * w;
      a3 += ht[k][3] * w;
    }
    const float bb = bo[c];
    out[(size_t)(b0r + 0) * C_ + c] = a0 + bb;
    out[(size_t)(b0r + 1) * C_ + c] = a1 + bb;
    out[(size_t)(b0r + 2) * C_ + c] = a2 + bb;
    out[(size_t)(b0r + 3) * C_ + c] = a3 + bb;
  }
}

extern "C" void kernel_launch(void* const* d_in, const int* in_sizes, int n_in,
                              void* d_out, int out_size, void* d_ws, size_t ws_size,
                              hipStream_t stream)
{
  const float* x   = (const float*)d_in[0];
  const float* W0x = (const float*)d_in[1];
  const float* W0h = (const float*)d_in[2];
  const float* b0  = (const float*)d_in[3];
  const float* W1x = (const float*)d_in[4];
  const float* W1h = (const float*)d_in[5];
  const float* b1  = (const float*)d_in[6];
  const float* Wo  = (const float*)d_in[7];
  const float* bo  = (const float*)d_in[8];

  const size_t slotB = (size_t)BH_ * sizeof(f16);              // 128KB per h slot
  const size_t xB    = (size_t)B_ * T_ * I_ * sizeof(f16);     // 8 MB
  // Tier A: write-once slots, no fences, fully decoupled layers (~73 MB).
  // Tier B: 24-slot ring, fence every 16 phases, L0-vs-L1 lag <= 7 (~14 MB).
  // Tier C: 2-slot ring, fence + lockstep-lag every phase (fallback).
  const size_t needA = 4096 + (size_t)2 * (T_ + 1) * slotB + xB;
  const size_t needB = 4096 + (size_t)2 * SLOTS_B_ * slotB + xB;
  int nslots, fmask, lagD;
  if (ws_size >= needA)      { nslots = T_ + 1;   fmask = -1; lagD = -1; }
  else if (ws_size >= needB) { nslots = SLOTS_B_; fmask = 15; lagD = 7;  }
  else                       { nslots = 2;        fmask = 0;  lagD = 0;  }
  const size_t histB = (size_t)nslots * slotB;

  unsigned* sync  = (unsigned*)d_ws;                 // arrival counters (4KB)
  f16* h0hist = (f16*)((char*)d_ws + 4096);
  f16* h1hist = (f16*)((char*)h0hist + histB);
  f16* x16    = (f16*)((char*)h1hist + histB);

  hipMemsetAsync(d_ws, 0, 4096 + slotB, stream);
  hipMemsetAsync(h1hist, 0, slotB, stream);

  hipLaunchKernelGGL(cvt_x, dim3((B_ * T_ * I_) / (256 * 8)), dim3(256), 0, stream, x, x16);

  hipLaunchKernelGGL(lstm_persistent, dim3(256), dim3(512), 0, stream,
                     x16, W0x, W0h, b0, W1x, W1h, b1, h0hist, h1hist, sync,
                     nslots, fmask, lagD);

  f16* h1fin = h1hist + (size_t)(T_ % nslots) * BH_;
  hipLaunchKernelGGL(out_gemm, dim3(8, 16), dim3(128), 0, stream,
                     h1fin, Wo, bo, (float*)d_out);
}

// Round 9
// 2530.126 us; speedup vs baseline: 1.0741x; 1.0741x over previous
//
#include <hip/hip_runtime.h>
#include <cstddef>

#define B_  64
#define T_  256
#define I_  256
#define H_  1024
#define C_  1000
#define BH_ (B_ * H_)
#define SLOTS_B_ 24        // ring length for the mid-size workspace tier

typedef _Float16 f16;
typedef __attribute__((ext_vector_type(8))) _Float16 f16x8;
typedef __attribute__((ext_vector_type(4))) float f32x4;

__device__ __forceinline__ float sigmoid_(float v) { return 1.0f / (1.0f + __expf(-v)); }
__device__ __forceinline__ float tanh_(float v) {
  float e = __expf(-2.0f * fabsf(v));
  float t = (1.0f - e) / (1.0f + e);
  return copysignf(t, v);
}

// h store: agent-scope relaxed atomic store -> write-through dword.
// Session lessons: 4B per-thread stores issued early drain under other
// waves' epilogue work; fancier packed 16B asm stores REGRESSED (R7).
__device__ __forceinline__ void storeH2(f16* p, float a, float b) {
  union { f16 h[2]; unsigned u; } pk;
  pk.h[0] = (f16)a; pk.h[1] = (f16)b;
  __hip_atomic_store((unsigned*)p, pk.u, __ATOMIC_RELAXED, __HIP_MEMORY_SCOPE_AGENT);
}

// ---------------- sync protocol (R2 leaderless min-gate; R4 arrangement) ---
// 4 closures of 64 blocks: C(layer,mgroup); 8 arrival counters each (128B
// lines), 8 adder-blocks per counter. Gate = min over own closure's 8
// counters >= 8p (induction: first block seeing min>=8p forces all counts=p).
// Adds AFTER the barrier's vmcnt(0) drain => observed arrival implies that
// block's h stores are visible at MALL.
// Gate placement (R4, measured best): L1's gate1 (C0) sits before its h0
// GEMM (pre-satisfied in tier A); gate2 (C1, the own-recurrence gate) sits
// AFTER the h0 GEMM so its wait hides under real work. R8's merged-gate
// variant exposed that wait and regressed -- do not merge.
// Session evidence (R4/R6 side-channel): total gate WAITS are ~0 (L0) and
// ~7% (L1) of the loop -- the phase period is the work path's dependent
// latency chain plus max-of-64 straggler dispersion, not poll contention
// (R0/R1), not chain hops beyond 3 (R2), not store width (R7).

__device__ __forceinline__ unsigned ldS(unsigned* p) {
  return __hip_atomic_load(p, __ATOMIC_RELAXED, __HIP_MEMORY_SCOPE_AGENT);
}

__device__ __forceinline__ void sleepN(int lvl) {
  switch (lvl) {
    case 0: __builtin_amdgcn_s_sleep(1); break;
    case 1: __builtin_amdgcn_s_sleep(2); break;
    case 2: __builtin_amdgcn_s_sleep(4); break;
    default: __builtin_amdgcn_s_sleep(8); break;
  }
}

__device__ __forceinline__ void waitCtr8(unsigned* base, unsigned tgt) {
  unsigned mn = 0xffffffffu;
#pragma unroll
  for (int j = 0; j < 8; ++j) {
    unsigned v = ldS(base + j * 32);
    mn = (v < mn) ? v : mn;
  }
  if (mn >= tgt) return;                         // fast path: 1 RT
  int lvl = 0, g = 0;
  for (;;) {
    mn = 0xffffffffu;
#pragma unroll
    for (int j = 0; j < 8; ++j) {
      unsigned v = ldS(base + j * 32);
      mn = (v < mn) ? v : mn;
    }
    if (mn >= tgt) break;
    sleepN(lvl);
    if (lvl < 3) ++lvl;                          // 64..512cy backoff
    if (++g > (1 << 17)) break;
  }
}

// One block = 512 threads = 8 waves = (K-split 4) x (N-split 2).
// Block tile: 32 batch rows x 64 gate-cols (4 gates x 16 units).
// k-tile map (per wave kq):
//   L0: ii<2 -> x-tile (immutable, computed PRE-gate); ii>=2 -> h0-tile.
//   L1: ii<8 -> h0-tile (gate1); ii>=8 -> h1-tile (gate2 after h0 GEMM).
// CRITICAL: prologue loop must stay FULLY unrolled so Wreg indexing is static.
template<bool IS_L1>
__device__ __forceinline__ void role_main(
    const f16* __restrict__ x16,
    const float* __restrict__ Wx, const float* __restrict__ Wh,
    const float* __restrict__ bias,
    f16* __restrict__ h0hist, f16* __restrict__ h1hist,
    unsigned* sync, int bid, int nslots, int fmask, int lagD,
    float* zbAll, float* cLDS, float* biasLDS)
{
  constexpr int NKT = IS_L1 ? 16 : 10;    // k-tiles of 32 per wave
  constexpr int KX  = IS_L1 ? 1024 : 256; // Wx/Wh k boundary

  const int tid  = threadIdx.x;
  const int wv   = tid >> 6;          // 0..7
  const int nh   = wv >> 2;           // col-half (32 cols each)
  const int kq   = wv & 3;            // K quarter
  const int lane = tid & 63;
  const int c16  = lane & 15;
  const int quad = lane >> 4;
  const int rr7  = bid & 127;
  const int mgroup  = rr7 & 1;
  const int ubase   = (rr7 >> 1) * 16;
  const int rowbase = mgroup * 32;

  const int sub = (rr7 >> 1) & 7;
  unsigned* ctrC0 = sync + ((0 * 2 + mgroup) * 8) * 32;
  unsigned* ctrC1 = sync + ((1 * 2 + mgroup) * 8) * 32;
  unsigned* arrLine = (IS_L1 ? ctrC1 : ctrC0) + sub * 32;

  auto kmap = [&](int ii) -> int {
    if (!IS_L1) return (ii < 2) ? (kq * 2 + ii) * 32 : 256 + (kq * 8 + (ii - 2)) * 32;
    else        return (ii < 8) ? (kq * 8 + ii) * 32 : 1024 + (kq * 8 + (ii - 8)) * 32;
  };

  if (tid < 64) biasLDS[tid] = bias[(size_t)(tid >> 4) * H_ + ubase + (tid & 15)];
  cLDS[tid] = 0.0f;

  // ---- weight prologue: global fp32 -> per-wave LDS panel -> f16 B-frags
  f16x8 Wreg[2][NKT];
  {
    f16* zpan = (f16*)zbAll + wv * 1024;
#pragma unroll
    for (int ii = 0; ii < NKT; ++ii) {
      const int kbase = kmap(ii);
#pragma unroll
      for (int rw = 0; rw < 16; ++rw) {
        const int krow  = rw * 2 + (lane >> 5);
        const int col32 = lane & 31;
        const int g = nh * 2 + (col32 >> 4);
        const int u = col32 & 15;
        const int k = kbase + krow;
        float wval = (k < KX) ? Wx[((size_t)g * KX + k) * H_ + ubase + u]
                              : Wh[((size_t)g * H_ + (k - KX)) * H_ + ubase + u];
        zpan[krow * 32 + col32] = (f16)wval;
      }
#pragma unroll
      for (int nt = 0; nt < 2; ++nt) {
        f16x8 f;
#pragma unroll
        for (int j = 0; j < 8; ++j)
          f[j] = zpan[(quad * 8 + j) * 32 + nt * 16 + c16];
        Wreg[nt][ii] = f;
      }
    }
  }
  __syncthreads();

  const int row0 = rowbase + c16;

#pragma unroll 1
  for (int p = 0; p <= T_; ++p) {
    const bool active = IS_L1 ? (p >= 1) : (p < T_);
    const int do_fence = (nslots == 2) ? 1
                        : ((fmask < 0) ? 0 : (((p & fmask) == fmask) ? 1 : 0));

    if (active) {
      const int sp  = p % nslots;
      const int spm = (p - 1 + nslots) % nslots;
      const int spp = (p + 1) % nslots;
      const f16* __restrict__ hA = h0hist + (size_t)sp * BH_;
      const f16* __restrict__ hB = h1hist + (size_t)spm * BH_;
      f16* __restrict__ hdst = IS_L1 ? (h1hist + (size_t)sp  * BH_)
                                     : (h0hist + (size_t)spp * BH_);

      f16x8 Abuf[8][2];
      auto loadTile = [&](int ii, int slot) {
        const int kb = kmap(ii) + quad * 8;
#pragma unroll
        for (int mt2 = 0; mt2 < 2; ++mt2) {
          const int row = row0 + mt2 * 16;
          const f16* src;
          if (!IS_L1) {
            src = (ii < 2) ? (x16 + ((size_t)row * T_ + p) * I_ + kb)
                           : (hA + (size_t)row * H_ + (kb - 256));
          } else {
            src = (ii < 8) ? (hA + (size_t)row * H_ + kb)
                           : (hB + (size_t)row * H_ + (kb - 1024));
          }
          Abuf[slot][mt2] = *(const f16x8*)src;
        }
      };

      f32x4 acc[2][2];
#pragma unroll
      for (int mt2 = 0; mt2 < 2; ++mt2)
#pragma unroll
        for (int nt = 0; nt < 2; ++nt)
          acc[mt2][nt] = (f32x4)0.0f;

      auto mfma4 = [&](int slot, int ii) {
        const f16x8 a0 = Abuf[slot][0];
        const f16x8 a1 = Abuf[slot][1];
        acc[0][0] = __builtin_amdgcn_mfma_f32_16x16x32_f16(a0, Wreg[0][ii], acc[0][0], 0, 0, 0);
        acc[0][1] = __builtin_amdgcn_mfma_f32_16x16x32_f16(a0, Wreg[1][ii], acc[0][1], 0, 0, 0);
        acc[1][0] = __builtin_amdgcn_mfma_f32_16x16x32_f16(a1, Wreg[0][ii], acc[1][0], 0, 0, 0);
        acc[1][1] = __builtin_amdgcn_mfma_f32_16x16x32_f16(a1, Wreg[1][ii], acc[1][1], 0, 0, 0);
      };

      if (!IS_L1) {
        // pre-gate x-part (immutable input, off the critical chain)
        loadTile(0, 0); loadTile(1, 1);
        mfma4(0, 0); mfma4(1, 1);
        if (tid == 0) {
          waitCtr8(ctrC0, 8u * (unsigned)p);
          if (lagD >= 0 && p > lagD) waitCtr8(ctrC1, 8u * (unsigned)(p - lagD));
          if (do_fence) __builtin_amdgcn_fence(__ATOMIC_ACQUIRE, "agent");
        }
        __syncthreads();
        // h-part: issue ALL loads, then MFMA (one MALL latency window)
#pragma unroll
        for (int ii = 2; ii < 10; ++ii) loadTile(ii, ii - 2);
#pragma unroll
        for (int ii = 2; ii < 10; ++ii) mfma4(ii - 2, ii);
      } else {
        // gate1: h0[p-1] ready (pre-satisfied in tier A: L0 runs ahead)
        if (tid == 0) {
          waitCtr8(ctrC0, 8u * (unsigned)p);
          if (do_fence) __builtin_amdgcn_fence(__ATOMIC_ACQUIRE, "agent");
        }
        __syncthreads();
#pragma unroll
        for (int ii = 0; ii < 8; ++ii) loadTile(ii, ii);
#pragma unroll
        for (int ii = 0; ii < 8; ++ii) mfma4(ii, ii);
        // gate2: own recurrence -- wait hides under the h0 GEMM above
        if (tid == 0) {
          waitCtr8(ctrC1, 8u * (unsigned)p);
          if (do_fence) __builtin_amdgcn_fence(__ATOMIC_ACQUIRE, "agent");
        }
        __syncthreads();
#pragma unroll
        for (int ii = 8; ii < 16; ++ii) loadTile(ii, ii - 8);
#pragma unroll
        for (int ii = 8; ii < 16; ++ii) mfma4(ii - 8, ii);
      }

      // partial z -> LDS; region (nh*4 + kq) so stage-1 sums stride-1024
      float* zw = zbAll + (nh * 4 + kq) * 1024;
#pragma unroll
      for (int mt2 = 0; mt2 < 2; ++mt2)
#pragma unroll
        for (int nt = 0; nt < 2; ++nt)
#pragma unroll
          for (int e = 0; e < 4; ++e)
            zw[(mt2 * 2 + nt) * 256 + (quad * 4 + e) * 16 + c16] = acc[mt2][nt][e];

      __syncthreads();

      // stage 1: reduce 4 K-partials + bias, in place into kq=0 region
      {
        const int base = tid * 4;
        const int nh1  = base >> 10;
        const int off  = base & 1023;
        f32x4 s = (f32x4)0.0f;
#pragma unroll
        for (int q = 0; q < 4; ++q)
          s += *(const f32x4*)(zbAll + nh1 * 4096 + q * 1024 + off);
        const int nt1 = (off >> 8) & 1;
        const int c0  = off & 15;
        s += *(const f32x4*)(biasLDS + (nh1 * 2 + nt1) * 16 + c0);
        *(f32x4*)(zbAll + nh1 * 4096 + off) = s;
      }
      __syncthreads();

      // stage 2: fused gates; c stays in LDS; h published write-through
      {
        const int row = tid >> 4, u = tid & 15;
        const int mt2 = row >> 4, r16 = row & 15;
        const float z0 = zbAll[0 * 4096 + (mt2 * 2 + 0) * 256 + r16 * 16 + u];
        const float z1 = zbAll[0 * 4096 + (mt2 * 2 + 1) * 256 + r16 * 16 + u];
        const float z2 = zbAll[1 * 4096 + (mt2 * 2 + 0) * 256 + r16 * 16 + u];
        const float z3 = zbAll[1 * 4096 + (mt2 * 2 + 1) * 256 + r16 * 16 + u];
        const float cv = cLDS[tid];
        const float gt = tanh_(z0);
        const float iv = sigmoid_(z1);
        const float fv = sigmoid_(z2);
        const float ov = sigmoid_(z3);
        const float cn = gt * iv + cv * fv;
        cLDS[tid] = cn;
        const float hn = tanh_(cn) * ov;
        const float hn_hi = __shfl_down(hn, 1);
        if ((tid & 1) == 0)
          storeH2(hdst + (size_t)(rowbase + row) * H_ + ubase + u, hn, hn_hi);
      }
    }

    __syncthreads();   // vmcnt(0) drain: all waves' h stores visible at MALL
    if (tid == 0)
      __hip_atomic_fetch_add(arrLine, 1u, __ATOMIC_RELAXED, __HIP_MEMORY_SCOPE_AGENT);
  }
}

__global__ __launch_bounds__(512, 2)
void lstm_persistent(const f16* __restrict__ x16,
                     const float* __restrict__ W0x, const float* __restrict__ W0h, const float* __restrict__ b0,
                     const float* __restrict__ W1x, const float* __restrict__ W1h, const float* __restrict__ b1,
                     f16* h0hist, f16* h1hist, unsigned* sync,
                     int nslots, int fmask, int lagD)
{
  __shared__ float zbAll[8192];    // 32KB: prologue panels / partial z / final z
  __shared__ float cLDS[512];
  __shared__ float biasLDS[64];
  const int bid = blockIdx.x;
  if (bid >= 128)
    role_main<true >(x16, W1x, W1h, b1, h0hist, h1hist, sync, bid, nslots, fmask, lagD, zbAll, cLDS, biasLDS);
  else
    role_main<false>(x16, W0x, W0h, b0, h0hist, h1hist, sync, bid, nslots, fmask, lagD, zbAll, cLDS, biasLDS);
}

// x fp32 -> f16, once
__global__ void cvt_x(const float* __restrict__ xin, f16* __restrict__ xo)
{
  const int i = (blockIdx.x * 256 + threadIdx.x) * 8;
  const float4 a = *(const float4*)(xin + i);
  const float4 b = *(const float4*)(xin + i + 4);
  f16x8 v;
  v[0] = (f16)a.x; v[1] = (f16)a.y; v[2] = (f16)a.z; v[3] = (f16)a.w;
  v[4] = (f16)b.x; v[5] = (f16)b.y; v[6] = (f16)b.z; v[7] = (f16)b.w;
  *(f16x8*)(xo + i) = v;
}

// out[b][c] = h1_final[b][:] . Wo[:][c] + bo[c]   (fp32 vector math)
__global__ void out_gemm(const f16* __restrict__ h1,
                         const float* __restrict__ Wo, const float* __restrict__ bo,
                         float* __restrict__ out)
{
  __shared__ float ht[1024][8];
  const int tid = threadIdx.x;    // 128 threads
  const int b0r = blockIdx.y * 4;
  for (int i = tid; i < 4096; i += 128) {
    const int rr = i >> 10, k = i & 1023;
    ht[k][rr] = (float)h1[(size_t)(b0r + rr) * H_ + k];
  }
  __syncthreads();
  const int c = blockIdx.x * 125 + tid;
  if (tid < 125) {
    float a0 = 0.f, a1 = 0.f, a2 = 0.f, a3 = 0.f;
#pragma unroll 4
    for (int k = 0; k < 1024; ++k) {
      const float w = Wo[(size_t)k * C_ + c];
      a0 += ht[k][0] * w;
      a1 += ht[k][1] * w;
      a2 += ht[k][2] * w;
      a3 += ht[k][3] * w;
    }
    const float bb = bo[c];
    out[(size_t)(b0r + 0) * C_ + c] = a0 + bb;
    out[(size_t)(b0r + 1) * C_ + c] = a1 + bb;
    out[(size_t)(b0r + 2) * C_ + c] = a2 + bb;
    out[(size_t)(b0r + 3) * C_ + c] = a3 + bb;
  }
}

extern "C" void kernel_launch(void* const* d_in, const int* in_sizes, int n_in,
                              void* d_out, int out_size, void* d_ws, size_t ws_size,
                              hipStream_t stream)
{
  const float* x   = (const float*)d_in[0];
  const float* W0x = (const float*)d_in[1];
  const float* W0h = (const float*)d_in[2];
  const float* b0  = (const float*)d_in[3];
  const float* W1x = (const float*)d_in[4];
  const float* W1h = (const float*)d_in[5];
  const float* b1  = (const float*)d_in[6];
  const float* Wo  = (const float*)d_in[7];
  const float* bo  = (const float*)d_in[8];

  const size_t slotB = (size_t)BH_ * sizeof(f16);              // 128KB per h slot
  const size_t xB    = (size_t)B_ * T_ * I_ * sizeof(f16);     // 8 MB
  // Tier A: write-once slots, no fences, fully decoupled layers (~73 MB).
  // Tier B: 24-slot ring, fence every 16 phases, L0-vs-L1 lag <= 7 (~14 MB).
  // Tier C: 2-slot ring, fence + lockstep-lag every phase (fallback).
  const size_t needA = 4096 + (size_t)2 * (T_ + 1) * slotB + xB;
  const size_t needB = 4096 + (size_t)2 * SLOTS_B_ * slotB + xB;
  int nslots, fmask, lagD;
  if (ws_size >= needA)      { nslots = T_ + 1;   fmask = -1; lagD = -1; }
  else if (ws_size >= needB) { nslots = SLOTS_B_; fmask = 15; lagD = 7;  }
  else                       { nslots = 2;        fmask = 0;  lagD = 0;  }
  const size_t histB = (size_t)nslots * slotB;

  unsigned* sync  = (unsigned*)d_ws;                 // arrival counters (4KB)
  f16* h0hist = (f16*)((char*)d_ws + 4096);
  f16* h1hist = (f16*)((char*)h0hist + histB);
  f16* x16    = (f16*)((char*)h1hist + histB);

  hipMemsetAsync(d_ws, 0, 4096 + slotB, stream);
  hipMemsetAsync(h1hist, 0, slotB, stream);

  hipLaunchKernelGGL(cvt_x, dim3((B_ * T_ * I_) / (256 * 8)), dim3(256), 0, stream, x, x16);

  hipLaunchKernelGGL(lstm_persistent, dim3(256), dim3(512), 0, stream,
                     x16, W0x, W0h, b0, W1x, W1h, b1, h0hist, h1hist, sync,
                     nslots, fmask, lagD);

  f16* h1fin = h1hist + (size_t)(T_ % nslots) * BH_;
  hipLaunchKernelGGL(out_gemm, dim3(8, 16), dim3(128), 0, stream,
                     h1fin, Wo, bo, (float*)d_out);
}

// Round 10
// 2441.474 us; speedup vs baseline: 1.1131x; 1.0363x over previous
//
#include <hip/hip_runtime.h>
#include <cstddef>

#define B_  64
#define T_  256
#define I_  256
#define H_  1024
#define C_  1000
#define BH_ (B_ * H_)
#define SLOTS_B_ 24        // ring length for the mid-size workspace tier

typedef _Float16 f16;
typedef __attribute__((ext_vector_type(8))) _Float16 f16x8;
typedef __attribute__((ext_vector_type(4))) float f32x4;

__device__ __forceinline__ float sigmoid_(float v) { return 1.0f / (1.0f + __expf(-v)); }
__device__ __forceinline__ float tanh_(float v) {
  float e = __expf(-2.0f * fabsf(v));
  float t = (1.0f - e) / (1.0f + e);
  return copysignf(t, v);
}

// h store: agent-scope relaxed atomic store -> write-through dword.
// Session lessons: 4B per-thread stores issued early drain under other
// waves' epilogue work; fancier packed 16B asm stores REGRESSED (R7).
__device__ __forceinline__ void storeH2(f16* p, float a, float b) {
  union { f16 h[2]; unsigned u; } pk;
  pk.h[0] = (f16)a; pk.h[1] = (f16)b;
  __hip_atomic_store((unsigned*)p, pk.u, __ATOMIC_RELAXED, __HIP_MEMORY_SCOPE_AGENT);
}

// ---------------- sync protocol (R2 leaderless min-gate; R4 arrangement) ---
// 4 closures of 64 blocks: C(layer,mgroup); 8 arrival counters each (128B
// lines), 8 adder-blocks per counter. Gate = min over own closure's 8
// counters >= 8p (induction: first block seeing min>=8p forces all counts=p).
// Adds AFTER the barrier's vmcnt(0) drain => observed arrival implies that
// block's h stores are visible at MALL.
// Gate placement (R4, measured best): L1's gate1 (C0) sits before its h0
// GEMM; gate2 (C1, own-recurrence) AFTER the h0 GEMM so its wait hides
// under real work. R8's merged-gate variant exposed that wait: regressed.
// R10: gate1 MONOTONIC CACHE. Counters never decrease, so one observation
// C0 >= 8*q licenses skipping gate1 polls for all phases p <= q (ordering
// inherited transitively from the barrier that followed the licensing
// poll). In tier A, L0 runs unboundedly ahead and finishes early -> the
// cache jumps to T+1 and gate1's ~0.7us satisfied-poll RT leaves L1's
// critical circle entirely. Gate2 is still polled every phase.

__device__ __forceinline__ unsigned ldS(unsigned* p) {
  return __hip_atomic_load(p, __ATOMIC_RELAXED, __HIP_MEMORY_SCOPE_AGENT);
}

__device__ __forceinline__ void sleepN(int lvl) {
  switch (lvl) {
    case 0: __builtin_amdgcn_s_sleep(1); break;
    case 1: __builtin_amdgcn_s_sleep(2); break;
    case 2: __builtin_amdgcn_s_sleep(4); break;
    default: __builtin_amdgcn_s_sleep(8); break;
  }
}

// one 8-line burst; returns min (1 fabric RT)
__device__ __forceinline__ unsigned probe8(unsigned* base) {
  unsigned mn = 0xffffffffu;
#pragma unroll
  for (int j = 0; j < 8; ++j) {
    unsigned v = ldS(base + j * 32);
    mn = (v < mn) ? v : mn;
  }
  return mn;
}

// spin until min >= tgt; returns the final observed min
__device__ __forceinline__ unsigned waitCtr8(unsigned* base, unsigned tgt) {
  unsigned mn = probe8(base);
  if (mn >= tgt) return mn;                      // fast path: 1 RT
  int lvl = 0, g = 0;
  for (;;) {
    mn = probe8(base);
    if (mn >= tgt) break;
    sleepN(lvl);
    if (lvl < 3) ++lvl;                          // 64..512cy backoff
    if (++g > (1 << 17)) break;
  }
  return mn;
}

// One block = 512 threads = 8 waves = (K-split 4) x (N-split 2).
// Block tile: 32 batch rows x 64 gate-cols (4 gates x 16 units).
// k-tile map (per wave kq):
//   L0: ii<2 -> x-tile (immutable, computed PRE-gate); ii>=2 -> h0-tile.
//   L1: ii<8 -> h0-tile (gate1); ii>=8 -> h1-tile (gate2 after h0 GEMM).
// CRITICAL: prologue loop must stay FULLY unrolled so Wreg indexing is static.
template<bool IS_L1>
__device__ __forceinline__ void role_main(
    const f16* __restrict__ x16,
    const float* __restrict__ Wx, const float* __restrict__ Wh,
    const float* __restrict__ bias,
    f16* __restrict__ h0hist, f16* __restrict__ h1hist,
    unsigned* sync, int bid, int nslots, int fmask, int lagD,
    float* zbAll, float* cLDS, float* biasLDS)
{
  constexpr int NKT = IS_L1 ? 16 : 10;    // k-tiles of 32 per wave
  constexpr int KX  = IS_L1 ? 1024 : 256; // Wx/Wh k boundary

  const int tid  = threadIdx.x;
  const int wv   = tid >> 6;          // 0..7
  const int nh   = wv >> 2;           // col-half (32 cols each)
  const int kq   = wv & 3;            // K quarter
  const int lane = tid & 63;
  const int c16  = lane & 15;
  const int quad = lane >> 4;
  const int rr7  = bid & 127;
  const int mgroup  = rr7 & 1;
  const int ubase   = (rr7 >> 1) * 16;
  const int rowbase = mgroup * 32;

  const int sub = (rr7 >> 1) & 7;
  unsigned* ctrC0 = sync + ((0 * 2 + mgroup) * 8) * 32;
  unsigned* ctrC1 = sync + ((1 * 2 + mgroup) * 8) * 32;
  unsigned* arrLine = (IS_L1 ? ctrC1 : ctrC0) + sub * 32;

  auto kmap = [&](int ii) -> int {
    if (!IS_L1) return (ii < 2) ? (kq * 2 + ii) * 32 : 256 + (kq * 8 + (ii - 2)) * 32;
    else        return (ii < 8) ? (kq * 8 + ii) * 32 : 1024 + (kq * 8 + (ii - 8)) * 32;
  };

  if (tid < 64) biasLDS[tid] = bias[(size_t)(tid >> 4) * H_ + ubase + (tid & 15)];
  cLDS[tid] = 0.0f;

  // ---- weight prologue: global fp32 -> per-wave LDS panel -> f16 B-frags
  f16x8 Wreg[2][NKT];
  {
    f16* zpan = (f16*)zbAll + wv * 1024;
#pragma unroll
    for (int ii = 0; ii < NKT; ++ii) {
      const int kbase = kmap(ii);
#pragma unroll
      for (int rw = 0; rw < 16; ++rw) {
        const int krow  = rw * 2 + (lane >> 5);
        const int col32 = lane & 31;
        const int g = nh * 2 + (col32 >> 4);
        const int u = col32 & 15;
        const int k = kbase + krow;
        float wval = (k < KX) ? Wx[((size_t)g * KX + k) * H_ + ubase + u]
                              : Wh[((size_t)g * H_ + (k - KX)) * H_ + ubase + u];
        zpan[krow * 32 + col32] = (f16)wval;
      }
#pragma unroll
      for (int nt = 0; nt < 2; ++nt) {
        f16x8 f;
#pragma unroll
        for (int j = 0; j < 8; ++j)
          f[j] = zpan[(quad * 8 + j) * 32 + nt * 16 + c16];
        Wreg[nt][ii] = f;
      }
    }
  }
  __syncthreads();

  const int row0 = rowbase + c16;
  int g1until = 0;                    // R10: highest phase gate1 is licensed for

#pragma unroll 1
  for (int p = 0; p <= T_; ++p) {
    const bool active = IS_L1 ? (p >= 1) : (p < T_);
    const int do_fence = (nslots == 2) ? 1
                        : ((fmask < 0) ? 0 : (((p & fmask) == fmask) ? 1 : 0));

    if (active) {
      const int sp  = p % nslots;
      const int spm = (p - 1 + nslots) % nslots;
      const int spp = (p + 1) % nslots;
      const f16* __restrict__ hA = h0hist + (size_t)sp * BH_;
      const f16* __restrict__ hB = h1hist + (size_t)spm * BH_;
      f16* __restrict__ hdst = IS_L1 ? (h1hist + (size_t)sp  * BH_)
                                     : (h0hist + (size_t)spp * BH_);

      f16x8 Abuf[8][2];
      auto loadTile = [&](int ii, int slot) {
        const int kb = kmap(ii) + quad * 8;
#pragma unroll
        for (int mt2 = 0; mt2 < 2; ++mt2) {
          const int row = row0 + mt2 * 16;
          const f16* src;
          if (!IS_L1) {
            src = (ii < 2) ? (x16 + ((size_t)row * T_ + p) * I_ + kb)
                           : (hA + (size_t)row * H_ + (kb - 256));
          } else {
            src = (ii < 8) ? (hA + (size_t)row * H_ + kb)
                           : (hB + (size_t)row * H_ + (kb - 1024));
          }
          Abuf[slot][mt2] = *(const f16x8*)src;
        }
      };

      f32x4 acc[2][2];
#pragma unroll
      for (int mt2 = 0; mt2 < 2; ++mt2)
#pragma unroll
        for (int nt = 0; nt < 2; ++nt)
          acc[mt2][nt] = (f32x4)0.0f;

      auto mfma4 = [&](int slot, int ii) {
        const f16x8 a0 = Abuf[slot][0];
        const f16x8 a1 = Abuf[slot][1];
        acc[0][0] = __builtin_amdgcn_mfma_f32_16x16x32_f16(a0, Wreg[0][ii], acc[0][0], 0, 0, 0);
        acc[0][1] = __builtin_amdgcn_mfma_f32_16x16x32_f16(a0, Wreg[1][ii], acc[0][1], 0, 0, 0);
        acc[1][0] = __builtin_amdgcn_mfma_f32_16x16x32_f16(a1, Wreg[0][ii], acc[1][0], 0, 0, 0);
        acc[1][1] = __builtin_amdgcn_mfma_f32_16x16x32_f16(a1, Wreg[1][ii], acc[1][1], 0, 0, 0);
      };

      if (!IS_L1) {
        // pre-gate x-part (immutable input, off the critical chain)
        loadTile(0, 0); loadTile(1, 1);
        mfma4(0, 0); mfma4(1, 1);
        if (tid == 0) {
          (void)waitCtr8(ctrC0, 8u * (unsigned)p);
          if (lagD >= 0 && p > lagD) (void)waitCtr8(ctrC1, 8u * (unsigned)(p - lagD));
          if (do_fence) __builtin_amdgcn_fence(__ATOMIC_ACQUIRE, "agent");
        }
        __syncthreads();
        // h-part: issue ALL loads, then MFMA (one MALL latency window)
#pragma unroll
        for (int ii = 2; ii < 10; ++ii) loadTile(ii, ii - 2);
#pragma unroll
        for (int ii = 2; ii < 10; ++ii) mfma4(ii - 2, ii);
      } else {
        // gate1: h0[p-1] ready. R10 monotone cache: poll only when the
        // cached license p <= g1until doesn't cover this phase.
        if (tid == 0) {
          if (p > g1until) {
            unsigned mn = probe8(ctrC0);                    // 1 RT
            if (mn < 8u * (unsigned)p)
              mn = waitCtr8(ctrC0, 8u * (unsigned)p);
            g1until = (int)(mn >> 3);   // license all phases <= floor(mn/8)
          }
          if (do_fence) __builtin_amdgcn_fence(__ATOMIC_ACQUIRE, "agent");
        }
        __syncthreads();
#pragma unroll
        for (int ii = 0; ii < 8; ++ii) loadTile(ii, ii);
#pragma unroll
        for (int ii = 0; ii < 8; ++ii) mfma4(ii, ii);
        // gate2: own recurrence -- wait hides under the h0 GEMM above
        if (tid == 0) {
          (void)waitCtr8(ctrC1, 8u * (unsigned)p);
          if (do_fence) __builtin_amdgcn_fence(__ATOMIC_ACQUIRE, "agent");
        }
        __syncthreads();
#pragma unroll
        for (int ii = 8; ii < 16; ++ii) loadTile(ii, ii - 8);
#pragma unroll
        for (int ii = 8; ii < 16; ++ii) mfma4(ii - 8, ii);
      }

      // partial z -> LDS; region (nh*4 + kq) so stage-1 sums stride-1024
      float* zw = zbAll + (nh * 4 + kq) * 1024;
#pragma unroll
      for (int mt2 = 0; mt2 < 2; ++mt2)
#pragma unroll
        for (int nt = 0; nt < 2; ++nt)
#pragma unroll
          for (int e = 0; e < 4; ++e)
            zw[(mt2 * 2 + nt) * 256 + (quad * 4 + e) * 16 + c16] = acc[mt2][nt][e];

      __syncthreads();

      // stage 1: reduce 4 K-partials + bias, in place into kq=0 region
      {
        const int base = tid * 4;
        const int nh1  = base >> 10;
        const int off  = base & 1023;
        f32x4 s = (f32x4)0.0f;
#pragma unroll
        for (int q = 0; q < 4; ++q)
          s += *(const f32x4*)(zbAll + nh1 * 4096 + q * 1024 + off);
        const int nt1 = (off >> 8) & 1;
        const int c0  = off & 15;
        s += *(const f32x4*)(biasLDS + (nh1 * 2 + nt1) * 16 + c0);
        *(f32x4*)(zbAll + nh1 * 4096 + off) = s;
      }
      __syncthreads();

      // stage 2: fused gates; c stays in LDS; h published write-through
      {
        const int row = tid >> 4, u = tid & 15;
        const int mt2 = row >> 4, r16 = row & 15;
        const float z0 = zbAll[0 * 4096 + (mt2 * 2 + 0) * 256 + r16 * 16 + u];
        const float z1 = zbAll[0 * 4096 + (mt2 * 2 + 1) * 256 + r16 * 16 + u];
        const float z2 = zbAll[1 * 4096 + (mt2 * 2 + 0) * 256 + r16 * 16 + u];
        const float z3 = zbAll[1 * 4096 + (mt2 * 2 + 1) * 256 + r16 * 16 + u];
        const float cv = cLDS[tid];
        const float gt = tanh_(z0);
        const float iv = sigmoid_(z1);
        const float fv = sigmoid_(z2);
        const float ov = sigmoid_(z3);
        const float cn = gt * iv + cv * fv;
        cLDS[tid] = cn;
        const float hn = tanh_(cn) * ov;
        const float hn_hi = __shfl_down(hn, 1);
        if ((tid & 1) == 0)
          storeH2(hdst + (size_t)(rowbase + row) * H_ + ubase + u, hn, hn_hi);
      }
    }

    __syncthreads();   // vmcnt(0) drain: all waves' h stores visible at MALL
    if (tid == 0)
      __hip_atomic_fetch_add(arrLine, 1u, __ATOMIC_RELAXED, __HIP_MEMORY_SCOPE_AGENT);
  }
}

__global__ __launch_bounds__(512, 2)
void lstm_persistent(const f16* __restrict__ x16,
                     const float* __restrict__ W0x, const float* __restrict__ W0h, const float* __restrict__ b0,
                     const float* __restrict__ W1x, const float* __restrict__ W1h, const float* __restrict__ b1,
                     f16* h0hist, f16* h1hist, unsigned* sync,
                     int nslots, int fmask, int lagD)
{
  __shared__ float zbAll[8192];    // 32KB: prologue panels / partial z / final z
  __shared__ float cLDS[512];
  __shared__ float biasLDS[64];
  const int bid = blockIdx.x;
  if (bid >= 128)
    role_main<true >(x16, W1x, W1h, b1, h0hist, h1hist, sync, bid, nslots, fmask, lagD, zbAll, cLDS, biasLDS);
  else
    role_main<false>(x16, W0x, W0h, b0, h0hist, h1hist, sync, bid, nslots, fmask, lagD, zbAll, cLDS, biasLDS);
}

// x fp32 -> f16, once
__global__ void cvt_x(const float* __restrict__ xin, f16* __restrict__ xo)
{
  const int i = (blockIdx.x * 256 + threadIdx.x) * 8;
  const float4 a = *(const float4*)(xin + i);
  const float4 b = *(const float4*)(xin + i + 4);
  f16x8 v;
  v[0] = (f16)a.x; v[1] = (f16)a.y; v[2] = (f16)a.z; v[3] = (f16)a.w;
  v[4] = (f16)b.x; v[5] = (f16)b.y; v[6] = (f16)b.z; v[7] = (f16)b.w;
  *(f16x8*)(xo + i) = v;
}

// out[b][c] = h1_final[b][:] . Wo[:][c] + bo[c]   (fp32 vector math)
__global__ void out_gemm(const f16* __restrict__ h1,
                         const float* __restrict__ Wo, const float* __restrict__ bo,
                         float* __restrict__ out)
{
  __shared__ float ht[1024][8];
  const int tid = threadIdx.x;    // 128 threads
  const int b0r = blockIdx.y * 4;
  for (int i = tid; i < 4096; i += 128) {
    const int rr = i >> 10, k = i & 1023;
    ht[k][rr] = (float)h1[(size_t)(b0r + rr) * H_ + k];
  }
  __syncthreads();
  const int c = blockIdx.x * 125 + tid;
  if (tid < 125) {
    float a0 = 0.f, a1 = 0.f, a2 = 0.f, a3 = 0.f;
#pragma unroll 4
    for (int k = 0; k < 1024; ++k) {
      const float w = Wo[(size_t)k * C_ + c];
      a0 += ht[k][0] * w;
      a1 += ht[k][1] * w;
      a2 += ht[k][2] * w;
      a3 += ht[k][3] * w;
    }
    const float bb = bo[c];
    out[(size_t)(b0r + 0) * C_ + c] = a0 + bb;
    out[(size_t)(b0r + 1) * C_ + c] = a1 + bb;
    out[(size_t)(b0r + 2) * C_ + c] = a2 + bb;
    out[(size_t)(b0r + 3) * C_ + c] = a3 + bb;
  }
}

extern "C" void kernel_launch(void* const* d_in, const int* in_sizes, int n_in,
                              void* d_out, int out_size, void* d_ws, size_t ws_size,
                              hipStream_t stream)
{
  const float* x   = (const float*)d_in[0];
  const float* W0x = (const float*)d_in[1];
  const float* W0h = (const float*)d_in[2];
  const float* b0  = (const float*)d_in[3];
  const float* W1x = (const float*)d_in[4];
  const float* W1h = (const float*)d_in[5];
  const float* b1  = (const float*)d_in[6];
  const float* Wo  = (const float*)d_in[7];
  const float* bo  = (const float*)d_in[8];

  const size_t slotB = (size_t)BH_ * sizeof(f16);              // 128KB per h slot
  const size_t xB    = (size_t)B_ * T_ * I_ * sizeof(f16);     // 8 MB
  // Tier A: write-once slots, no fences, fully decoupled layers (~73 MB).
  // Tier B: 24-slot ring, fence every 16 phases, L0-vs-L1 lag <= 7 (~14 MB).
  // Tier C: 2-slot ring, fence + lockstep-lag every phase (fallback).
  const size_t needA = 4096 + (size_t)2 * (T_ + 1) * slotB + xB;
  const size_t needB = 4096 + (size_t)2 * SLOTS_B_ * slotB + xB;
  int nslots, fmask, lagD;
  if (ws_size >= needA)      { nslots = T_ + 1;   fmask = -1; lagD = -1; }
  else if (ws_size >= needB) { nslots = SLOTS_B_; fmask = 15; lagD = 7;  }
  else                       { nslots = 2;        fmask = 0;  lagD = 0;  }
  const size_t histB = (size_t)nslots * slotB;

  unsigned* sync  = (unsigned*)d_ws;                 // arrival counters (4KB)
  f16* h0hist = (f16*)((char*)d_ws + 4096);
  f16* h1hist = (f16*)((char*)h0hist + histB);
  f16* x16    = (f16*)((char*)h1hist + histB);

  hipMemsetAsync(d_ws, 0, 4096 + slotB, stream);
  hipMemsetAsync(h1hist, 0, slotB, stream);

  hipLaunchKernelGGL(cvt_x, dim3((B_ * T_ * I_) / (256 * 8)), dim3(256), 0, stream, x, x16);

  hipLaunchKernelGGL(lstm_persistent, dim3(256), dim3(512), 0, stream,
                     x16, W0x, W0h, b0, W1x, W1h, b1, h0hist, h1hist, sync,
                     nslots, fmask, lagD);

  f16* h1fin = h1hist + (size_t)(T_ % nslots) * BH_;
  hipLaunchKernelGGL(out_gemm, dim3(8, 16), dim3(128), 0, stream,
                     h1fin, Wo, bo, (float*)d_out);
}